// Round 6
// baseline (104.303 us; speedup 1.0000x reference)
//
#include <hip/hip_runtime.h>

#define NPT 384
#define NB 2
#define NROW (NB*NPT)        // 768
#define NT 6                 // j-tiles per row
#define HOFF 49152           // start of x section in d_out
#define RECB 1024            // bytes per partial record
#define REC_OFF 424960       // byte offset of records in d_ws

typedef unsigned short u16;
typedef unsigned int u32;
typedef __bf16 bf16x8 __attribute__((ext_vector_type(8)));
typedef float f32x4 __attribute__((ext_vector_type(4)));

struct alignas(16) U4 { u32 x, y, z, w; };
struct alignas(8)  U2 { u32 x, y; };

constexpr float kEPS = 1e-5f;
constexpr float kINF = 1e5f;

__device__ __forceinline__ u16 f2b(float f) { __bf16 b = (__bf16)f; return __builtin_bit_cast(u16, b); }
__device__ __forceinline__ u32 pk2(float lo, float hi) { return (u32)f2b(lo) | ((u32)f2b(hi) << 16); }
__device__ __forceinline__ float b2f(u32 u) { return __uint_as_float(u << 16); }
__device__ __forceinline__ float silu_f(float v) { return v * __builtin_amdgcn_rcpf(1.f + __expf(-v)); }
__device__ __forceinline__ float wredmax(float v) {
#pragma unroll
  for (int m = 32; m >= 1; m >>= 1) v = fmaxf(v, __shfl_xor(v, m, 64));
  return v;
}
__device__ __forceinline__ float wredsum(float v) {
#pragma unroll
  for (int m = 32; m >= 1; m >>= 1) v += __shfl_xor(v, m, 64);
  return v;
}
__device__ __forceinline__ void up8(U4 u, float* f) {
  f[0] = b2f(u.x & 0xffffu); f[1] = b2f(u.x >> 16);
  f[2] = b2f(u.y & 0xffffu); f[3] = b2f(u.y >> 16);
  f[4] = b2f(u.z & 0xffffu); f[5] = b2f(u.z >> 16);
  f[6] = b2f(u.w & 0xffffu); f[7] = b2f(u.w >> 16);
}

// ---------------- prep: U = h@We0[:64]+be0, V = h@We0[64:128]; bf16 transposed weight images ----------------
__global__ __launch_bounds__(64) void sake_prep(
    const float* __restrict__ h, const float* __restrict__ We0,
    const float* __restrict__ be0, const float* __restrict__ We1,
    const float* __restrict__ Wc0, const float* __restrict__ Wc1,
    const float* __restrict__ Wx0, const float* __restrict__ Ws,
    float* __restrict__ U, float* __restrict__ V, u16* __restrict__ WT)
{
  const int t = threadIdx.x;
  const int blk = blockIdx.x;
  if (blk < NROW) {
    __shared__ float hs[64];
    hs[t] = h[blk * 64 + t];
    __syncthreads();
    float u = be0[t], v = 0.f;
#pragma unroll 8
    for (int k = 0; k < 64; k++) {
      float hv = hs[k];
      u = fmaf(hv, We0[k * 64 + t], u);
      v = fmaf(hv, We0[(64 + k) * 64 + t], v);
    }
    U[blk * 64 + t] = u;
    V[blk * 64 + t] = v;
  } else {
    const int wsel = blk - NROW;
    if (wsel == 4) {
      u16* dst = WT + 14336;     // WsPT: 16x64, rows 4..15 zero
      for (int o = t; o < 16 * 64; o += 64) {
        int c = o >> 6, k = o & 63;
        dst[o] = (c < 4) ? f2b(Ws[k * 4 + c]) : (u16)0;
      }
      return;
    }
    const float* src; int nout; u16* dst;
    if      (wsel == 0) { src = We1; nout = 64; dst = WT;         }
    else if (wsel == 1) { src = Wc0; nout = 64; dst = WT + 4096;  }
    else if (wsel == 2) { src = Wx0; nout = 64; dst = WT + 8192;  }
    else                { src = Wc1; nout = 32; dst = WT + 12288; }
    const int total = 64 * nout;
    for (int o = t; o < total; o += 64) {
      int n = o >> 6, k = o & 63;
      dst[o] = f2b(src[k * nout + n]);
    }
  }
}

// ---------------- main: one block per (row, j-tile) ----------------
struct MainArgs {
  const float *x, *U, *V;
  const u16 *We1T, *Wc0T, *Wx0T, *Wc1T, *WsPT;
  const float *We0, *bs, *be1, *bc0, *bc1, *bx0, *Wx1, *log_gamma;
  char* rec;
};

// b-fragment (data) read: row j of a swizzled row-major [64][64] bf16 LDS tile.
__device__ __forceinline__ void readB(const u16* tile, int j, int kg, bf16x8& f0, bf16x8& f1) {
  const int r7 = j & 7;
  f0 = *(const bf16x8*)(tile + j * 64 + ((kg ^ r7) << 3));
  f1 = *(const bf16x8*)(tile + j * 64 + (((kg + 4) ^ r7) << 3));
}

// Transposed-orientation GEMM: OUT[j][n] for j in this wave's stripe, n = 0..16*NNT-1.
// A_op = WT[n][k] (global, [n][64] bf16), B_op = data rows (b-frags passed in, loop-invariant).
// Lane's acc quad = features n0..n0+3 of row j -> one packed b64 store per nt.
// Output tile row-major [64][NCH*8] u16, chunk-swizzled with (chunk ^ (j & (NCH-1))).
// DUALT additionally writes transposed copy oTT[f][j] with R3's verified hesT swizzle.
template<int NNT, bool SILU_, int NCH, bool DUALT>
__device__ __forceinline__ void gemmT(const u16* __restrict__ wG, const float* __restrict__ biasG,
                                      bf16x8 bf0, bf16x8 bf1, u16* out, u16* oTT, int w, int lane)
{
  const int j = (w << 4) + (lane & 15);
  const int kg = lane >> 4;
  const int jm = j & (NCH - 1);
#pragma unroll
  for (int nt = 0; nt < NNT; nt++) {
    const int nrow = (nt << 4) + (lane & 15);
    bf16x8 a0 = *(const bf16x8*)(wG + nrow * 64 + (kg << 3));
    bf16x8 a1 = *(const bf16x8*)(wG + nrow * 64 + 32 + (kg << 3));
    f32x4 acc = {0.f, 0.f, 0.f, 0.f};
    acc = __builtin_amdgcn_mfma_f32_16x16x32_bf16(a0, bf0, acc, 0, 0, 0);
    acc = __builtin_amdgcn_mfma_f32_16x16x32_bf16(a1, bf1, acc, 0, 0, 0);
    const int n0 = (nt << 4) + (kg << 2);
    const float4 bv = *(const float4*)(biasG + n0);
    float s0, s1, s2, s3;
    if constexpr (SILU_) {
      s0 = silu_f(acc[0] + bv.x); s1 = silu_f(acc[1] + bv.y);
      s2 = silu_f(acc[2] + bv.z); s3 = silu_f(acc[3] + bv.w);
    } else {
      s0 = acc[0] + bv.x; s1 = acc[1] + bv.y;
      s2 = acc[2] + bv.z; s3 = acc[3] + bv.w;
    }
    const u16 q0 = f2b(s0), q1 = f2b(s1), q2 = f2b(s2), q3 = f2b(s3);
    U2 pkd; pkd.x = (u32)q0 | ((u32)q1 << 16); pkd.y = (u32)q2 | ((u32)q3 << 16);
    const int c = n0 >> 3;
    *(U2*)(out + j * (NCH * 8) + (((c ^ jm) << 3) + (n0 & 7))) = pkd;
    if constexpr (DUALT) {
      const int jq = (j >> 3), j7 = j & 7;
      const u16 qs[4] = {q0, q1, q2, q3};
#pragma unroll
      for (int r = 0; r < 4; r++) {
        const int f = n0 + r;
        oTT[f * 64 + ((jq ^ (f & 7)) << 3) + j7] = qs[r];
      }
    }
  }
}

__global__ __launch_bounds__(256, 4) void sake_main(MainArgs A)
{
  __shared__ __align__(16) u16 buf0[64 * 64];   // h1 / c1 / s1 ; then cA/xA f32 stash
  __shared__ __align__(16) u16 hes[64 * 64];    // h_e row-major swizzled
  __shared__ __align__(16) u16 hesT[64 * 64];   // h_e transposed swizzled (R3-verified layout)
  __shared__ __align__(16) u16 coeff[64 * 32];  // coeff, NCH=4 swizzle
  __shared__ __align__(16) u16 E_lds[16 * 64];  // E tile, R3-verified swizzle (rows 4..15 garbage, discarded)
  __shared__ float raw_lds[64 * 5];             // sem logits [j][head] (R3-verified path)
  __shared__ float disp[64][3];
  __shared__ float nrm_s[64];

  const int t = threadIdx.x;
  const int w = t >> 6, lane = t & 63;
  const int bt = blockIdx.x;
  const int i = bt % NPT;
  const int bj = bt / NPT;          // b*NT + jt
  const int jt = bj % NT, b = bj / NT;
  const int bi = b * NPT + i;
  const int j0 = jt << 6;
  const int jj2 = t >> 2, q4 = t & 3;
  char* rec = A.rec + (size_t)(bi * NT + jt) * RECB;

  // ---- independent global loads ----
  const int jrow = j0 + jj2;
  const float* xp = &A.x[(b * NPT + jrow) * 3];
  const float xj0 = xp[0], xj1 = xp[1], xj2 = xp[2];
  const float xi0 = A.x[bi * 3 + 0], xi1 = A.x[bi * 3 + 1], xi2 = A.x[bi * 3 + 2];
  const float4* vp = (const float4*)(A.V + (size_t)(b * NPT + jrow) * 64 + q4 * 16);
  const float4 v0_ = vp[0], v1_ = vp[1], v2_ = vp[2], v3_ = vp[3];
  const float4* Up = (const float4*)(A.U + bi * 64 + q4 * 16);
  const float4 u0_ = Up[0], u1_ = Up[1], u2_ = Up[2], u3_ = Up[3];
  const float4* Wd = (const float4*)(A.We0 + 128 * 64 + q4 * 16);
  const float4 w0_ = Wd[0], w1_ = Wd[1], w2_ = Wd[2], w3_ = Wd[3];

  // ---- stage h1 = silu(u_i + v_j + norm*wd) for row jj2 (stripe-local) ----
  {
    float dx0 = xi0 - xj0, dx1 = xi1 - xj1, dx2 = xi2 - xj2;
    float nr = sqrtf(fmaf(dx0, dx0, fmaf(dx1, dx1, fmaf(dx2, dx2, kEPS))));
    if (q4 == 0) { disp[jj2][0] = dx0; disp[jj2][1] = dx1; disp[jj2][2] = dx2; nrm_s[jj2] = nr; }
    float vv[16] = {v0_.x, v0_.y, v0_.z, v0_.w, v1_.x, v1_.y, v1_.z, v1_.w,
                    v2_.x, v2_.y, v2_.z, v2_.w, v3_.x, v3_.y, v3_.z, v3_.w};
    float uu[16] = {u0_.x, u0_.y, u0_.z, u0_.w, u1_.x, u1_.y, u1_.z, u1_.w,
                    u2_.x, u2_.y, u2_.z, u2_.w, u3_.x, u3_.y, u3_.z, u3_.w};
    float ww[16] = {w0_.x, w0_.y, w0_.z, w0_.w, w1_.x, w1_.y, w1_.z, w1_.w,
                    w2_.x, w2_.y, w2_.z, w2_.w, w3_.x, w3_.y, w3_.z, w3_.w};
    float sv[16];
#pragma unroll
    for (int e = 0; e < 16; e++) sv[e] = silu_f(uu[e] + vv[e] + nr * ww[e]);
    U4 lo, hi;
    lo.x = pk2(sv[0], sv[1]);   lo.y = pk2(sv[2], sv[3]);
    lo.z = pk2(sv[4], sv[5]);   lo.w = pk2(sv[6], sv[7]);
    hi.x = pk2(sv[8], sv[9]);   hi.y = pk2(sv[10], sv[11]);
    hi.z = pk2(sv[12], sv[13]); hi.w = pk2(sv[14], sv[15]);
    const int r7 = jj2 & 7;
    *(U4*)(buf0 + jj2 * 64 + (((q4 * 2) ^ r7) << 3)) = lo;
    *(U4*)(buf0 + jj2 * 64 + (((q4 * 2 + 1) ^ r7) << 3)) = hi;
  }

  const int j = (w << 4) + (lane & 15);
  const int kg = lane >> 4;

  // ---- h_e = silu(h1 @ We1 + be1), dual write (row-major + R3-layout transpose) ----
  bf16x8 bh0, bh1;
  readB(buf0, j, kg, bh0, bh1);
  gemmT<4, true, 8, true>(A.We1T, A.be1, bh0, bh1, hes, hesT, w, lane);

  bf16x8 he0, he1;
  readB(hes, j, kg, he0, he1);

  // ---- c1 = silu(h_e @ Wc0 + bc0) ----
  gemmT<4, true, 8, false>(A.Wc0T, A.bc0, he0, he1, buf0, nullptr, w, lane);
  // ---- coeff = c1 @ Wc1 + bc1 ----
  bf16x8 c10, c11;
  readB(buf0, j, kg, c10, c11);
  gemmT<2, false, 4, false>(A.Wc1T, A.bc1, c10, c11, coeff, nullptr, w, lane);

  // ---- combinations partial: cA[c] += coeff[j][c]/(nr+eps) * disp[j][d] ----
  float cA0 = 0, cA1 = 0, cA2 = 0, xA0 = 0, xA1 = 0, xA2 = 0;
  {
    const int c = t & 31, g = t >> 5;   // rows (g<<3)+it are in this wave's stripe
    const int cc = c >> 3, ce = c & 7;
#pragma unroll
    for (int it = 0; it < 8; ++it) {
      const int jj = (g << 3) + it;
      const float s = b2f(coeff[jj * 32 + ((cc ^ (jj & 3)) << 3) + ce]) *
                      __builtin_amdgcn_rcpf(nrm_s[jj] + kEPS);
      cA0 = fmaf(s, disp[jj][0], cA0);
      cA1 = fmaf(s, disp[jj][1], cA1);
      cA2 = fmaf(s, disp[jj][2], cA2);
    }
  }

  // ---- s1 = silu(h_e @ Wx0 + bx0) ----
  gemmT<4, true, 8, false>(A.Wx0T, A.bx0, he0, he1, buf0, nullptr, w, lane);

  // ---- scale = s1 @ Wx1 ; coordinate partial ----
  {
    const int jj = jj2;
    const int r7 = jj & 7;
    float acc = 0.f;
#pragma unroll
    for (int c2 = 0; c2 < 2; c2++) {
      const int c = q4 * 2 + c2;
      U4 u = *(const U4*)(buf0 + jj * 64 + ((c ^ r7) << 3));
      float f8[8]; up8(u, f8);
      const float4* wx = (const float4*)(A.Wx1 + c * 8);
      const float4 wxa = wx[0], wxb = wx[1];
      acc = fmaf(f8[0], wxa.x, acc); acc = fmaf(f8[1], wxa.y, acc);
      acc = fmaf(f8[2], wxa.z, acc); acc = fmaf(f8[3], wxa.w, acc);
      acc = fmaf(f8[4], wxb.x, acc); acc = fmaf(f8[5], wxb.y, acc);
      acc = fmaf(f8[6], wxb.z, acc); acc = fmaf(f8[7], wxb.w, acc);
    }
    acc += __shfl_xor(acc, 1, 64);
    acc += __shfl_xor(acc, 2, 64);
    if (q4 == 0) {
      xA0 = fmaf(disp[jj][0], acc, xA0);
      xA1 = fmaf(disp[jj][1], acc, xA1);
      xA2 = fmaf(disp[jj][2], acc, xA2);
    }
  }

  // ---- semantic logits, R3-verified orientation: A = h_e rows, B = WsPT -> raw_lds[j][head] ----
  {
    const int m0 = w << 4;
    const int arow = m0 + (lane & 15);
    const int r7a = arow & 7;
    bf16x8 a0 = *(const bf16x8*)(hes + arow * 64 + ((kg ^ r7a) << 3));
    bf16x8 a1 = *(const bf16x8*)(hes + arow * 64 + (((kg + 4) ^ r7a) << 3));
    const u16* wrow = A.WsPT + (lane & 15) * 64;
    bf16x8 b0 = *(const bf16x8*)(wrow + (kg << 3));
    bf16x8 b1 = *(const bf16x8*)(wrow + 32 + (kg << 3));
    f32x4 acc = {0.f, 0.f, 0.f, 0.f};
    acc = __builtin_amdgcn_mfma_f32_16x16x32_bf16(a0, b0, acc, 0, 0, 0);
    acc = __builtin_amdgcn_mfma_f32_16x16x32_bf16(a1, b1, acc, 0, 0, 0);
    if ((lane & 15) < 4) {
#pragma unroll
      for (int r = 0; r < 4; r++)
        raw_lds[(m0 + (kg << 2) + r) * 5 + (lane & 15)] = acc[r];
    }
  }
  __syncthreads();   // SYNC_B: raw_lds, nrm_s, hes/hesT complete; s1/coeff reads done

  // ---- stash cA/xA partials in buf0 (dead) ----
  float* cascr = (float*)buf0;
  float* xscr = (float*)buf0 + 768;
  cascr[t * 3 + 0] = cA0; cascr[t * 3 + 1] = cA1; cascr[t * 3 + 2] = cA2;
  if (q4 == 0) { xscr[jj2 * 3 + 0] = xA0; xscr[jj2 * 3 + 1] = xA1; xscr[jj2 * 3 + 2] = xA2; }

  // ---- per-tile softmax stats (head = w, j = lane); E into E_lds, R3-verified swizzle ----
  {
    const int jj = lane, head = w;
    float raw = raw_lds[jj * 5 + head] + A.bs[head];
    float bsem = (raw > 0.f) ? raw : 0.2f * raw;
    const bool self = (j0 + jj) == i;
    if (self) bsem -= kINF;
    const float gam = __expf(A.log_gamma[head]);
    const float aeu = -(nrm_s[jj] + (self ? kINF : 0.f)) * gam;
    const float L = aeu + bsem;
    const float mL = wredmax(L);
    const float eL = __expf(L - mL);
    const float SL = wredsum(eL);
    const float mb = wredmax(bsem);
    const float Sb = wredsum(__expf(bsem - mb));
    const float Sa = wredsum(__expf(aeu));
    E_lds[head * 64 + (((jj >> 3) ^ head) << 3) + (jj & 7)] = f2b(eL);
    if (lane == 0) {
      float* sp = (float*)(rec + 908) + head * 5;
      sp[0] = mL; sp[1] = SL; sp[2] = mb; sp[3] = Sb; sp[4] = Sa;
    }
  }
  __syncthreads();   // SYNC_C: E + stash ready

  // ---- A partial via MFMA (R3-verified): A[head][f] = sum_j eL[j] * h_e[j][f] ----
  {
    const int erow = lane & 15;
    const int e7 = erow & 7;
    bf16x8 ea0 = *(const bf16x8*)(E_lds + erow * 64 + ((kg ^ e7) << 3));
    bf16x8 ea1 = *(const bf16x8*)(E_lds + erow * 64 + (((kg + 4) ^ e7) << 3));
    const int f = (w << 4) + (lane & 15);
    const int f7 = f & 7;
    bf16x8 hb0 = *(const bf16x8*)(hesT + f * 64 + ((kg ^ f7) << 3));
    bf16x8 hb1 = *(const bf16x8*)(hesT + f * 64 + (((kg + 4) ^ f7) << 3));
    f32x4 aF = {0.f, 0.f, 0.f, 0.f};
    aF = __builtin_amdgcn_mfma_f32_16x16x32_bf16(ea0, hb0, aF, 0, 0, 0);
    aF = __builtin_amdgcn_mfma_f32_16x16x32_bf16(ea1, hb1, aF, 0, 0, 0);
    if (kg == 0) {
      u16* rA = (u16*)rec;
#pragma unroll
      for (int r = 0; r < 4; r++) rA[r * 64 + f] = f2b(aF[r]);
    }
  }
  // ---- reduce cA/xA partials -> record ----
  if (t < 96) {
    const int c = t & 31, d = t >> 5;
    float s = 0.f;
#pragma unroll
    for (int g = 0; g < 8; g++) s += cascr[(g * 32 + c) * 3 + d];
    ((float*)(rec + 512))[d * 32 + c] = s;
  } else if (t < 99) {
    const int d = t - 96;
    float s = 0.f;
    for (int k = 0; k < 64; k++) s += xscr[k * 3 + d];
    ((float*)(rec + 896))[d] = s;
  }
}

// ---------------- merge: one block per row; softmax-merge + finalize MLPs ----------------
struct MergeArgs {
  const float *h, *x, *Wp0, *bp0, *Wp1, *bp1, *Wn0, *bn0, *Wn1, *bn1;
  const char* rec;
  float* out;
};

__global__ __launch_bounds__(256) void sake_merge(MergeArgs M)
{
  __shared__ float sc[NT][20];
  __shared__ float wAl[NT][4];
  __shared__ float coefh[4];
  __shared__ float node_in[384];
  __shared__ float cmv[96];
  __shared__ float nrm32[32];
  __shared__ float t0s[64];
  __shared__ float scr[256];

  const int t = threadIdx.x;
  const int bi = blockIdx.x;
  const char* rb = M.rec + (size_t)bi * NT * RECB;

  if (t < NT * 20) {
    const int tt = t / 20, k = t % 20;
    sc[tt][k] = ((const float*)(rb + tt * RECB + 908))[k];
  }
  if (t < 64) node_in[t] = M.h[bi * 64 + t];
  __syncthreads();
  if (t < 4) {
    const int hh = t;
    float mL = -1e30f, mb = -1e30f;
    for (int tt = 0; tt < NT; tt++) {
      mL = fmaxf(mL, sc[tt][hh * 5 + 0]);
      mb = fmaxf(mb, sc[tt][hh * 5 + 2]);
    }
    float SL = 0.f, Sb = 0.f, Sa = 0.f;
    for (int tt = 0; tt < NT; tt++) {
      const float wa = __expf(sc[tt][hh * 5 + 0] - mL);
      wAl[tt][hh] = wa;
      SL = fmaf(wa, sc[tt][hh * 5 + 1], SL);
      Sb = fmaf(__expf(sc[tt][hh * 5 + 2] - mb), sc[tt][hh * 5 + 3], Sb);
      Sa += sc[tt][hh * 5 + 4];
    }
    const float Ff = __expf(mL - mb);
    coefh[hh] = Ff / fmaf(SL, Ff, kEPS * Sa * Sb);
  }
  __syncthreads();
  {  // h_e_agg
    const int hh = t >> 6, f = t & 63;
    float s = 0.f;
#pragma unroll
    for (int tt = 0; tt < NT; tt++)
      s = fmaf(wAl[tt][hh], b2f(((const u16*)(rb + tt * RECB))[hh * 64 + f]), s);
    node_in[64 + hh * 64 + f] = s * coefh[hh];
  }
  if (t < 96) {
    float s = 0.f;
#pragma unroll
    for (int tt = 0; tt < NT; tt++) s += ((const float*)(rb + tt * RECB + 512))[t];
    cmv[t] = s * (1.f / 384.f);
  }
  if (t >= 128 && t < 131) {
    const int d = t - 128;
    float s = 0.f;
#pragma unroll
    for (int tt = 0; tt < NT; tt++) s += ((const float*)(rb + tt * RECB + 896))[d];
    M.out[HOFF + bi * 3 + d] = M.x[bi * 3 + d] + s * (1.f / 384.f);
  }
  __syncthreads();
  if (t < 32) {
    const float v0 = cmv[t], v1 = cmv[32 + t], v2 = cmv[64 + t];
    nrm32[t] = v0 * v0 + v1 * v1 + v2 * v2;
  }
  __syncthreads();
  if (t < 64) {
    float a = M.bp0[t];
    for (int c = 0; c < 32; c++) a = fmaf(nrm32[c], M.Wp0[c * 64 + t], a);
    t0s[t] = silu_f(a);
  }
  __syncthreads();
  if (t < 64) {
    float a = M.bp1[t];
    for (int k = 0; k < 64; k++) a = fmaf(t0s[k], M.Wp1[k * 64 + t], a);
    node_in[320 + t] = a;
  }
  __syncthreads();
  {
    const int f = t & 63, q = t >> 6;
    float a = 0.f;
    const int k0 = q * 96;
    for (int k = 0; k < 96; k++) a = fmaf(node_in[k0 + k], M.Wn0[(k0 + k) * 64 + f], a);
    scr[t] = a;
  }
  __syncthreads();
  if (t < 64) {
    const float s = scr[t] + scr[64 + t] + scr[128 + t] + scr[192 + t] + M.bn0[t];
    t0s[t] = silu_f(s);
  }
  __syncthreads();
  if (t < 64) {
    float a = M.bn1[t];
    for (int k = 0; k < 64; k++) a = fmaf(t0s[k], M.Wn1[k * 64 + t], a);
    M.out[bi * 64 + t] = M.h[bi * 64 + t] + a;
  }
}

extern "C" void kernel_launch(void* const* d_in, const int* in_sizes, int n_in,
                              void* d_out, int out_size, void* d_ws, size_t ws_size,
                              hipStream_t stream)
{
  (void)in_sizes; (void)n_in; (void)out_size; (void)ws_size;
  const float* h   = (const float*)d_in[0];
  const float* x   = (const float*)d_in[1];
  const float* We0 = (const float*)d_in[2];
  const float* be0 = (const float*)d_in[3];
  const float* We1 = (const float*)d_in[4];
  const float* be1 = (const float*)d_in[5];
  const float* Ws  = (const float*)d_in[6];
  const float* bs  = (const float*)d_in[7];
  const float* Wc0 = (const float*)d_in[8];
  const float* bc0 = (const float*)d_in[9];
  const float* Wc1 = (const float*)d_in[10];
  const float* bc1 = (const float*)d_in[11];
  const float* Wp0 = (const float*)d_in[12];
  const float* bp0 = (const float*)d_in[13];
  const float* Wp1 = (const float*)d_in[14];
  const float* bp1 = (const float*)d_in[15];
  const float* Wx0 = (const float*)d_in[16];
  const float* bx0 = (const float*)d_in[17];
  const float* Wx1 = (const float*)d_in[18];
  const float* Wn0 = (const float*)d_in[19];
  const float* bn0 = (const float*)d_in[20];
  const float* Wn1 = (const float*)d_in[21];
  const float* bn1 = (const float*)d_in[22];
  const float* lg  = (const float*)d_in[23];

  float* U = (float*)d_ws;
  float* V = U + NROW * 64;
  u16* WT = (u16*)(V + NROW * 64);
  char* rec = (char*)d_ws + REC_OFF;

  sake_prep<<<NROW + 5, 64, 0, stream>>>(h, We0, be0, We1, Wc0, Wc1, Wx0, Ws, U, V, WT);

  MainArgs A;
  A.x = x; A.U = U; A.V = V;
  A.We1T = WT; A.Wc0T = WT + 4096; A.Wx0T = WT + 8192; A.Wc1T = WT + 12288;
  A.WsPT = WT + 14336;
  A.We0 = We0; A.bs = bs; A.be1 = be1; A.bc0 = bc0; A.bc1 = bc1;
  A.bx0 = bx0; A.Wx1 = Wx1; A.log_gamma = lg;
  A.rec = rec;
  sake_main<<<NROW * NT, 256, 0, stream>>>(A);

  MergeArgs Mg;
  Mg.h = h; Mg.x = x;
  Mg.Wp0 = Wp0; Mg.bp0 = bp0; Mg.Wp1 = Wp1; Mg.bp1 = bp1;
  Mg.Wn0 = Wn0; Mg.bn0 = bn0; Mg.Wn1 = Wn1; Mg.bn1 = bn1;
  Mg.rec = rec; Mg.out = (float*)d_out;
  sake_merge<<<NROW, 256, 0, stream>>>(Mg);
}

// Round 7
// 99.943 us; speedup vs baseline: 1.0436x; 1.0436x over previous
//
#include <hip/hip_runtime.h>

#define NPT 384
#define NB 2
#define NROW (NB*NPT)        // 768
#define NT 6                 // j-tiles per row
#define HOFF 49152           // start of x section in d_out
#define RECB 1024            // bytes per partial record
#define REC_OFF 424960       // byte offset of records in d_ws

typedef unsigned short u16;
typedef unsigned int u32;
typedef __bf16 bf16x8 __attribute__((ext_vector_type(8)));
typedef float f32x4 __attribute__((ext_vector_type(4)));

struct alignas(16) U4 { u32 x, y, z, w; };

constexpr float kEPS = 1e-5f;
constexpr float kINF = 1e5f;

__device__ __forceinline__ u16 f2b(float f) { __bf16 b = (__bf16)f; return __builtin_bit_cast(u16, b); }
__device__ __forceinline__ u32 pk2(float lo, float hi) { return (u32)f2b(lo) | ((u32)f2b(hi) << 16); }
__device__ __forceinline__ float b2f(u32 u) { return __uint_as_float(u << 16); }
__device__ __forceinline__ float silu_f(float v) { return v * __builtin_amdgcn_rcpf(1.f + __expf(-v)); }
__device__ __forceinline__ float wredmax(float v) {
#pragma unroll
  for (int m = 32; m >= 1; m >>= 1) v = fmaxf(v, __shfl_xor(v, m, 64));
  return v;
}
__device__ __forceinline__ float wredsum(float v) {
#pragma unroll
  for (int m = 32; m >= 1; m >>= 1) v += __shfl_xor(v, m, 64);
  return v;
}
__device__ __forceinline__ void up8(U4 u, float* f) {
  f[0] = b2f(u.x & 0xffffu); f[1] = b2f(u.x >> 16);
  f[2] = b2f(u.y & 0xffffu); f[3] = b2f(u.y >> 16);
  f[4] = b2f(u.z & 0xffffu); f[5] = b2f(u.z >> 16);
  f[6] = b2f(u.w & 0xffffu); f[7] = b2f(u.w >> 16);
}

// ---------------- prep: U = h@We0[:64]+be0, V = h@We0[64:128]; bf16 transposed weight images ----------------
__global__ __launch_bounds__(64) void sake_prep(
    const float* __restrict__ h, const float* __restrict__ We0,
    const float* __restrict__ be0, const float* __restrict__ We1,
    const float* __restrict__ Wc0, const float* __restrict__ Wc1,
    const float* __restrict__ Wx0, const float* __restrict__ Ws,
    float* __restrict__ U, float* __restrict__ V, u16* __restrict__ WT)
{
  const int t = threadIdx.x;
  const int blk = blockIdx.x;
  if (blk < NROW) {
    __shared__ float hs[64];
    hs[t] = h[blk * 64 + t];
    __syncthreads();
    float u = be0[t], v = 0.f;
#pragma unroll 8
    for (int k = 0; k < 64; k++) {
      float hv = hs[k];
      u = fmaf(hv, We0[k * 64 + t], u);
      v = fmaf(hv, We0[(64 + k) * 64 + t], v);
    }
    U[blk * 64 + t] = u;
    V[blk * 64 + t] = v;
  } else {
    const int wsel = blk - NROW;
    if (wsel == 4) {
      u16* dst = WT + 14336;     // WsPT: 16x64, rows 4..15 zero
      for (int o = t; o < 16 * 64; o += 64) {
        int c = o >> 6, k = o & 63;
        dst[o] = (c < 4) ? f2b(Ws[k * 4 + c]) : (u16)0;
      }
      return;
    }
    const float* src; int nout; u16* dst;
    if      (wsel == 0) { src = We1; nout = 64; dst = WT;         }
    else if (wsel == 1) { src = Wc0; nout = 64; dst = WT + 4096;  }
    else if (wsel == 2) { src = Wx0; nout = 64; dst = WT + 8192;  }
    else                { src = Wc1; nout = 32; dst = WT + 12288; }
    const int total = 64 * nout;
    for (int o = t; o < total; o += 64) {
      int n = o >> 6, k = o & 63;
      dst[o] = f2b(src[k * nout + n]);
    }
  }
}

// ---------------- main: one block per (row, j-tile), 8 waves ----------------
struct MainArgs {
  const float *x, *U, *V;
  const u16 *We1T, *Wc0T, *Wx0T, *Wc1T, *WsPT;
  const float *We0, *bs, *be1, *bc0, *bc1, *bx0, *Wx1, *log_gamma;
  char* rec;
};

// b-fragment (data) read: row j of a swizzled row-major [64][64] bf16 LDS tile.
__device__ __forceinline__ void readB(const u16* tile, int j, int kg, bf16x8& f0, bf16x8& f1) {
  const int r7 = j & 7;
  f0 = *(const bf16x8*)(tile + j * 64 + ((kg ^ r7) << 3));
  f1 = *(const bf16x8*)(tile + j * 64 + (((kg + 4) ^ r7) << 3));
}

// Transposed-orientation GEMM, 8-wave version: wave covers rows of its stripe (via j),
// output cols nbase .. nbase + NNT*16 - 1.  A_op = WT[n][k] global image, B_op = data row frags.
// Output row-major [64][NCH*8] u16, chunk-swizzled (chunk ^ (j & (NCH-1))).
// DUALT also writes transposed oTT[f][j] with the R6-verified swizzle.
template<int NNT, bool SILU_, int NCH, bool DUALT>
__device__ __forceinline__ void gemmT8(const u16* __restrict__ wG, const float* __restrict__ biasG,
                                       bf16x8 bf0, bf16x8 bf1, u16* out, u16* oTT,
                                       int j, int kg, int l15, int nbase)
{
  const int jm = j & (NCH - 1);
#pragma unroll
  for (int nt = 0; nt < NNT; nt++) {
    const int nrow = nbase + (nt << 4) + l15;
    bf16x8 a0 = *(const bf16x8*)(wG + nrow * 64 + (kg << 3));
    bf16x8 a1 = *(const bf16x8*)(wG + nrow * 64 + 32 + (kg << 3));
    f32x4 acc = {0.f, 0.f, 0.f, 0.f};
    acc = __builtin_amdgcn_mfma_f32_16x16x32_bf16(a0, bf0, acc, 0, 0, 0);
    acc = __builtin_amdgcn_mfma_f32_16x16x32_bf16(a1, bf1, acc, 0, 0, 0);
    const int n0 = nbase + (nt << 4) + (kg << 2);
    const float4 bv = *(const float4*)(biasG + n0);
    float s0, s1, s2, s3;
    if constexpr (SILU_) {
      s0 = silu_f(acc[0] + bv.x); s1 = silu_f(acc[1] + bv.y);
      s2 = silu_f(acc[2] + bv.z); s3 = silu_f(acc[3] + bv.w);
    } else {
      s0 = acc[0] + bv.x; s1 = acc[1] + bv.y;
      s2 = acc[2] + bv.z; s3 = acc[3] + bv.w;
    }
    const u16 q0 = f2b(s0), q1 = f2b(s1), q2 = f2b(s2), q3 = f2b(s3);
    u32 pkx = (u32)q0 | ((u32)q1 << 16), pky = (u32)q2 | ((u32)q3 << 16);
    const int c = n0 >> 3;
    u32* dst = (u32*)(out + j * (NCH * 8) + (((c ^ jm) << 3) + (n0 & 7)));
    dst[0] = pkx; dst[1] = pky;
    if constexpr (DUALT) {
      const int jq = (j >> 3), j7 = j & 7;
      const u16 qs[4] = {q0, q1, q2, q3};
#pragma unroll
      for (int r = 0; r < 4; r++) {
        const int f = n0 + r;
        oTT[f * 64 + ((jq ^ (f & 7)) << 3) + j7] = qs[r];
      }
    }
  }
}

__global__ __launch_bounds__(512, 8) void sake_main(MainArgs A)
{
  __shared__ __align__(16) u16 buf0[64 * 64];   // h1 / c1 / s1 ; then cA stash (f32)
  __shared__ __align__(16) u16 hes[64 * 64];    // h_e row-major swizzled ; then xA stash
  __shared__ __align__(16) u16 hesT[64 * 64];   // h_e transposed swizzled
  __shared__ __align__(16) u16 coeff[64 * 32];  // coeff, NCH=4 swizzle
  __shared__ __align__(16) u16 E_lds[16 * 64];  // E tile (rows 4..15 garbage -> discarded D rows)
  __shared__ float raw_lds[64 * 5];             // sem logits [j][head]
  __shared__ float disp[64][3];
  __shared__ float nrm_s[64];

  const int t = threadIdx.x;
  const int w = t >> 6, lane = t & 63;
  const int rs = w >> 1, ch = w & 1;            // row-stripe, col-half
  const int kg = lane >> 4, l15 = lane & 15;
  const int bt = blockIdx.x;
  const int i = bt % NPT;
  const int bj = bt / NPT;
  const int jt = bj % NT, b = bj / NT;
  const int bi = b * NPT + i;
  const int j0 = jt << 6;
  char* rec = A.rec + (size_t)(bi * NT + jt) * RECB;

  // ================= P0: stage h1 = silu(u_i + v_j + nr*wd); 8 threads/row =================
  const int jj3 = t >> 3, q8 = t & 7;
  {
    const int jrow = j0 + jj3;
    const float* xp = &A.x[(b * NPT + jrow) * 3];
    const float xj0 = xp[0], xj1 = xp[1], xj2 = xp[2];
    const float xi0 = A.x[bi * 3 + 0], xi1 = A.x[bi * 3 + 1], xi2 = A.x[bi * 3 + 2];
    const float4* vp = (const float4*)(A.V + (size_t)(b * NPT + jrow) * 64 + q8 * 8);
    const float4 v0_ = vp[0], v1_ = vp[1];
    const float4* Up = (const float4*)(A.U + bi * 64 + q8 * 8);
    const float4 u0_ = Up[0], u1_ = Up[1];
    const float4* Wd = (const float4*)(A.We0 + 128 * 64 + q8 * 8);
    const float4 w0_ = Wd[0], w1_ = Wd[1];
    float dx0 = xi0 - xj0, dx1 = xi1 - xj1, dx2 = xi2 - xj2;
    float nr = sqrtf(fmaf(dx0, dx0, fmaf(dx1, dx1, fmaf(dx2, dx2, kEPS))));
    if (q8 == 0) { disp[jj3][0] = dx0; disp[jj3][1] = dx1; disp[jj3][2] = dx2; nrm_s[jj3] = nr; }
    float vv[8] = {v0_.x, v0_.y, v0_.z, v0_.w, v1_.x, v1_.y, v1_.z, v1_.w};
    float uu[8] = {u0_.x, u0_.y, u0_.z, u0_.w, u1_.x, u1_.y, u1_.z, u1_.w};
    float ww[8] = {w0_.x, w0_.y, w0_.z, w0_.w, w1_.x, w1_.y, w1_.z, w1_.w};
    float sv[8];
#pragma unroll
    for (int e = 0; e < 8; e++) sv[e] = silu_f(uu[e] + vv[e] + nr * ww[e]);
    U4 u4;
    u4.x = pk2(sv[0], sv[1]); u4.y = pk2(sv[2], sv[3]);
    u4.z = pk2(sv[4], sv[5]); u4.w = pk2(sv[6], sv[7]);
    *(U4*)(buf0 + jj3 * 64 + ((q8 ^ (jj3 & 7)) << 3)) = u4;
  }
  __syncthreads();   // B1: h1 staged

  const int jrow16 = (rs << 4) + l15;   // this wave's MFMA data row
  const int nb64 = ch << 5;             // col base for 64-wide outputs

  // ================= P1: h_e = silu(h1 @ We1 + be1), dual write =================
  {
    bf16x8 bh0, bh1;
    readB(buf0, jrow16, kg, bh0, bh1);
    gemmT8<2, true, 8, true>(A.We1T, A.be1, bh0, bh1, hes, hesT, jrow16, kg, l15, nb64);
  }
  __syncthreads();   // B2: hes/hesT complete; h1 reads done

  bf16x8 he0, he1;
  readB(hes, jrow16, kg, he0, he1);

  // ================= P2: c1 = silu(h_e @ Wc0 + bc0) -> buf0 =================
  gemmT8<2, true, 8, false>(A.Wc0T, A.bc0, he0, he1, buf0, nullptr, jrow16, kg, l15, nb64);
  __syncthreads();   // B3: c1 complete

  // ================= P3: coeff = c1 @ Wc1 + bc1 ; sem logits (ch==0 waves) =================
  {
    bf16x8 c10, c11;
    readB(buf0, jrow16, kg, c10, c11);
    gemmT8<1, false, 4, false>(A.Wc1T, A.bc1, c10, c11, coeff, nullptr, jrow16, kg, l15, ch << 4);
  }
  if (ch == 0) {
    // R6-verified orientation: A = hes rows of this stripe, B = WsPT -> raw_lds[j][head]
    const int m0 = rs << 4;
    const int arow = m0 + l15;
    const int r7a = arow & 7;
    bf16x8 a0 = *(const bf16x8*)(hes + arow * 64 + ((kg ^ r7a) << 3));
    bf16x8 a1 = *(const bf16x8*)(hes + arow * 64 + (((kg + 4) ^ r7a) << 3));
    const u16* wrow = A.WsPT + l15 * 64;
    bf16x8 b0 = *(const bf16x8*)(wrow + (kg << 3));
    bf16x8 b1 = *(const bf16x8*)(wrow + 32 + (kg << 3));
    f32x4 acc = {0.f, 0.f, 0.f, 0.f};
    acc = __builtin_amdgcn_mfma_f32_16x16x32_bf16(a0, b0, acc, 0, 0, 0);
    acc = __builtin_amdgcn_mfma_f32_16x16x32_bf16(a1, b1, acc, 0, 0, 0);
    if (l15 < 4) {
#pragma unroll
      for (int r = 0; r < 4; r++)
        raw_lds[(m0 + (kg << 2) + r) * 5 + l15] = acc[r];
    }
  }
  __syncthreads();   // B4: coeff + raw complete; c1 reads done

  // ================= P4: combinations partial ; s1 = silu(h_e @ Wx0 + bx0) -> buf0 =================
  float cA0 = 0, cA1 = 0, cA2 = 0, xA0 = 0, xA1 = 0, xA2 = 0;
  {
    const int c = t & 31, g = t >> 5;   // 16 groups x 4 rows
    const int cc = c >> 3, ce = c & 7;
#pragma unroll
    for (int it = 0; it < 4; ++it) {
      const int jj = (g << 2) + it;
      const float s = b2f(coeff[jj * 32 + ((cc ^ (jj & 3)) << 3) + ce]) *
                      __builtin_amdgcn_rcpf(nrm_s[jj] + kEPS);
      cA0 = fmaf(s, disp[jj][0], cA0);
      cA1 = fmaf(s, disp[jj][1], cA1);
      cA2 = fmaf(s, disp[jj][2], cA2);
    }
  }
  gemmT8<2, true, 8, false>(A.Wx0T, A.bx0, he0, he1, buf0, nullptr, jrow16, kg, l15, nb64);
  __syncthreads();   // B5: s1 complete

  // ================= P5a: waves 0..3 softmax stats ; waves 4..7 scale/coordinate partial =================
  float mL_r = 0.f, SL_r = 0.f, mb_r = 0.f, Sb_r = 0.f, Sa_r = 0.f;   // only waves 0..3
  if (w < 4) {
    const int jj = lane, head = w;
    float raw = raw_lds[jj * 5 + head] + A.bs[head];
    float bsem = (raw > 0.f) ? raw : 0.2f * raw;
    const bool self = (j0 + jj) == i;
    if (self) bsem -= kINF;
    const float gam = __expf(A.log_gamma[head]);
    const float aeu = -(nrm_s[jj] + (self ? kINF : 0.f)) * gam;
    const float L = aeu + bsem;
    const float mL = wredmax(L);
    const float eL = __expf(L - mL);
    const float SL = wredsum(eL);
    const float mb = wredmax(bsem);
    const float Sb = wredsum(__expf(bsem - mb));
    const float Sa = wredsum(__expf(aeu));
    E_lds[head * 64 + (((jj >> 3) ^ head) << 3) + (jj & 7)] = f2b(eL);
    mL_r = mL; SL_r = SL; mb_r = mb; Sb_r = Sb; Sa_r = Sa;
  } else {
    const int tp = t - 256;
    const int jj = tp >> 2, q4 = tp & 3;
    const int r7 = jj & 7;
    float acc = 0.f;
#pragma unroll
    for (int c2 = 0; c2 < 2; c2++) {
      const int c = q4 * 2 + c2;
      U4 u = *(const U4*)(buf0 + jj * 64 + ((c ^ r7) << 3));
      float f8[8]; up8(u, f8);
      const float4* wx = (const float4*)(A.Wx1 + c * 8);
      const float4 wxa = wx[0], wxb = wx[1];
      acc = fmaf(f8[0], wxa.x, acc); acc = fmaf(f8[1], wxa.y, acc);
      acc = fmaf(f8[2], wxa.z, acc); acc = fmaf(f8[3], wxa.w, acc);
      acc = fmaf(f8[4], wxb.x, acc); acc = fmaf(f8[5], wxb.y, acc);
      acc = fmaf(f8[6], wxb.z, acc); acc = fmaf(f8[7], wxb.w, acc);
    }
    acc += __shfl_xor(acc, 1, 64);
    acc += __shfl_xor(acc, 2, 64);
    if (q4 == 0) {
      xA0 = disp[jj][0] * acc;
      xA1 = disp[jj][1] * acc;
      xA2 = disp[jj][2] * acc;
    }
  }
  if (w < 4 && lane == 0) {
    float* sp = (float*)(rec + 908) + w * 5;
    sp[0] = mL_r; sp[1] = SL_r; sp[2] = mb_r; sp[3] = Sb_r; sp[4] = Sa_r;
  }
  __syncthreads();   // B6: E + s1 reads done

  // ================= P5b: stash partials ; waves 0..3 A-accum MFMA =================
  float* cascr = (float*)buf0;            // 512*3 f32 = 6144B within buf0
  float* xscr = (float*)hes;              // 64*3 f32, hes dead
  cascr[t * 3 + 0] = cA0; cascr[t * 3 + 1] = cA1; cascr[t * 3 + 2] = cA2;
  if (w >= 4 && ((t - 256) & 3) == 0) {
    const int jj = (t - 256) >> 2;
    xscr[jj * 3 + 0] = xA0; xscr[jj * 3 + 1] = xA1; xscr[jj * 3 + 2] = xA2;
  }
  if (w < 4) {
    const int erow = l15;
    const int e7 = erow & 7;
    bf16x8 ea0 = *(const bf16x8*)(E_lds + erow * 64 + ((kg ^ e7) << 3));
    bf16x8 ea1 = *(const bf16x8*)(E_lds + erow * 64 + (((kg + 4) ^ e7) << 3));
    const int f = (w << 4) + l15;
    const int f7 = f & 7;
    bf16x8 hb0 = *(const bf16x8*)(hesT + f * 64 + ((kg ^ f7) << 3));
    bf16x8 hb1 = *(const bf16x8*)(hesT + f * 64 + (((kg + 4) ^ f7) << 3));
    f32x4 aF = {0.f, 0.f, 0.f, 0.f};
    aF = __builtin_amdgcn_mfma_f32_16x16x32_bf16(ea0, hb0, aF, 0, 0, 0);
    aF = __builtin_amdgcn_mfma_f32_16x16x32_bf16(ea1, hb1, aF, 0, 0, 0);
    if (kg == 0) {
      u16* rA = (u16*)rec;
#pragma unroll
      for (int r = 0; r < 4; r++) rA[r * 64 + f] = f2b(aF[r]);
    }
  }
  __syncthreads();   // B7: stashes ready

  // ================= P6: reduce partials -> record =================
  if (t < 96) {
    const int c = t & 31, d = t >> 5;
    float s = 0.f;
#pragma unroll
    for (int g = 0; g < 16; g++) s += cascr[(g * 32 + c) * 3 + d];
    ((float*)(rec + 512))[d * 32 + c] = s;
  } else if (t < 99) {
    const int d = t - 96;
    float s = 0.f;
    for (int k = 0; k < 64; k++) s += xscr[k * 3 + d];
    ((float*)(rec + 896))[d] = s;
  }
}

// ---------------- merge: one block per row; softmax-merge + finalize MLPs ----------------
struct MergeArgs {
  const float *h, *x, *Wp0, *bp0, *Wp1, *bp1, *Wn0, *bn0, *Wn1, *bn1;
  const char* rec;
  float* out;
};

__global__ __launch_bounds__(256) void sake_merge(MergeArgs M)
{
  __shared__ float sc[NT][20];
  __shared__ float wAl[NT][4];
  __shared__ float coefh[4];
  __shared__ float node_in[384];
  __shared__ float cmv[96];
  __shared__ float nrm32[32];
  __shared__ float t0s[64];
  __shared__ float scr[256];

  const int t = threadIdx.x;
  const int bi = blockIdx.x;
  const char* rb = M.rec + (size_t)bi * NT * RECB;

  if (t < NT * 20) {
    const int tt = t / 20, k = t % 20;
    sc[tt][k] = ((const float*)(rb + tt * RECB + 908))[k];
  }
  if (t < 64) node_in[t] = M.h[bi * 64 + t];
  __syncthreads();
  if (t < 4) {
    const int hh = t;
    float mL = -1e30f, mb = -1e30f;
    for (int tt = 0; tt < NT; tt++) {
      mL = fmaxf(mL, sc[tt][hh * 5 + 0]);
      mb = fmaxf(mb, sc[tt][hh * 5 + 2]);
    }
    float SL = 0.f, Sb = 0.f, Sa = 0.f;
    for (int tt = 0; tt < NT; tt++) {
      const float wa = __expf(sc[tt][hh * 5 + 0] - mL);
      wAl[tt][hh] = wa;
      SL = fmaf(wa, sc[tt][hh * 5 + 1], SL);
      Sb = fmaf(__expf(sc[tt][hh * 5 + 2] - mb), sc[tt][hh * 5 + 3], Sb);
      Sa += sc[tt][hh * 5 + 4];
    }
    const float Ff = __expf(mL - mb);
    coefh[hh] = Ff / fmaf(SL, Ff, kEPS * Sa * Sb);
  }
  __syncthreads();
  {  // h_e_agg
    const int hh = t >> 6, f = t & 63;
    float s = 0.f;
#pragma unroll
    for (int tt = 0; tt < NT; tt++)
      s = fmaf(wAl[tt][hh], b2f(((const u16*)(rb + tt * RECB))[hh * 64 + f]), s);
    node_in[64 + hh * 64 + f] = s * coefh[hh];
  }
  if (t < 96) {
    float s = 0.f;
#pragma unroll
    for (int tt = 0; tt < NT; tt++) s += ((const float*)(rb + tt * RECB + 512))[t];
    cmv[t] = s * (1.f / 384.f);
  }
  if (t >= 128 && t < 131) {
    const int d = t - 128;
    float s = 0.f;
#pragma unroll
    for (int tt = 0; tt < NT; tt++) s += ((const float*)(rb + tt * RECB + 896))[d];
    M.out[HOFF + bi * 3 + d] = M.x[bi * 3 + d] + s * (1.f / 384.f);
  }
  __syncthreads();
  if (t < 32) {
    const float v0 = cmv[t], v1 = cmv[32 + t], v2 = cmv[64 + t];
    nrm32[t] = v0 * v0 + v1 * v1 + v2 * v2;
  }
  __syncthreads();
  if (t < 64) {
    float a = M.bp0[t];
    for (int c = 0; c < 32; c++) a = fmaf(nrm32[c], M.Wp0[c * 64 + t], a);
    t0s[t] = silu_f(a);
  }
  __syncthreads();
  if (t < 64) {
    float a = M.bp1[t];
    for (int k = 0; k < 64; k++) a = fmaf(t0s[k], M.Wp1[k * 64 + t], a);
    node_in[320 + t] = a;
  }
  __syncthreads();
  {
    const int f = t & 63, q = t >> 6;
    float a = 0.f;
    const int k0 = q * 96;
    for (int k = 0; k < 96; k++) a = fmaf(node_in[k0 + k], M.Wn0[(k0 + k) * 64 + f], a);
    scr[t] = a;
  }
  __syncthreads();
  if (t < 64) {
    const float s = scr[t] + scr[64 + t] + scr[128 + t] + scr[192 + t] + M.bn0[t];
    t0s[t] = silu_f(s);
  }
  __syncthreads();
  if (t < 64) {
    float a = M.bn1[t];
    for (int k = 0; k < 64; k++) a = fmaf(t0s[k], M.Wn1[k * 64 + t], a);
    M.out[bi * 64 + t] = M.h[bi * 64 + t] + a;
  }
}

extern "C" void kernel_launch(void* const* d_in, const int* in_sizes, int n_in,
                              void* d_out, int out_size, void* d_ws, size_t ws_size,
                              hipStream_t stream)
{
  (void)in_sizes; (void)n_in; (void)out_size; (void)ws_size;
  const float* h   = (const float*)d_in[0];
  const float* x   = (const float*)d_in[1];
  const float* We0 = (const float*)d_in[2];
  const float* be0 = (const float*)d_in[3];
  const float* We1 = (const float*)d_in[4];
  const float* be1 = (const float*)d_in[5];
  const float* Ws  = (const float*)d_in[6];
  const float* bs  = (const float*)d_in[7];
  const float* Wc0 = (const float*)d_in[8];
  const float* bc0 = (const float*)d_in[9];
  const float* Wc1 = (const float*)d_in[10];
  const float* bc1 = (const float*)d_in[11];
  const float* Wp0 = (const float*)d_in[12];
  const float* bp0 = (const float*)d_in[13];
  const float* Wp1 = (const float*)d_in[14];
  const float* bp1 = (const float*)d_in[15];
  const float* Wx0 = (const float*)d_in[16];
  const float* bx0 = (const float*)d_in[17];
  const float* Wx1 = (const float*)d_in[18];
  const float* Wn0 = (const float*)d_in[19];
  const float* bn0 = (const float*)d_in[20];
  const float* Wn1 = (const float*)d_in[21];
  const float* bn1 = (const float*)d_in[22];
  const float* lg  = (const float*)d_in[23];

  float* U = (float*)d_ws;
  float* V = U + NROW * 64;
  u16* WT = (u16*)(V + NROW * 64);
  char* rec = (char*)d_ws + REC_OFF;

  sake_prep<<<NROW + 5, 64, 0, stream>>>(h, We0, be0, We1, Wc0, Wc1, Wx0, Ws, U, V, WT);

  MainArgs A;
  A.x = x; A.U = U; A.V = V;
  A.We1T = WT; A.Wc0T = WT + 4096; A.Wx0T = WT + 8192; A.Wc1T = WT + 12288;
  A.WsPT = WT + 14336;
  A.We0 = We0; A.bs = bs; A.be1 = be1; A.bc0 = bc0; A.bc1 = bc1;
  A.bx0 = bx0; A.Wx1 = Wx1; A.log_gamma = lg;
  A.rec = rec;
  sake_main<<<NROW * NT, 512, 0, stream>>>(A);

  MergeArgs Mg;
  Mg.h = h; Mg.x = x;
  Mg.Wp0 = Wp0; Mg.bp0 = bp0; Mg.Wp1 = Wp1; Mg.bp1 = bp1;
  Mg.Wn0 = Wn0; Mg.bn0 = bn0; Mg.Wn1 = Wn1; Mg.bn1 = bn1;
  Mg.rec = rec; Mg.out = (float*)d_out;
  sake_merge<<<NROW, 256, 0, stream>>>(Mg);
}